// Round 7
// baseline (1220.723 us; speedup 1.0000x reference)
//
#include <hip/hip_runtime.h>
#include <cmath>

#define BATCH 2
#define LSEQ 2048
#define DMODEL 1024
#define DINNER 2048
#define NHEADS 32
#define DHEAD 64
#define DSTATE 64
#define DCONV 4
#define CONVDIM (DINNER + 2*DSTATE)            // 2176
#define DINPROJ (2*DINNER + 2*DSTATE + NHEADS) // 4256
#define DINPROJ_PAD 4352                       // 34*128
#define CHUNKSZ 256
#define NCHUNK (LSEQ/CHUNKSZ)                  // 8
#define MROWS (BATCH*LSEQ)                     // 4096
#define EPSF 1e-5f

typedef __attribute__((ext_vector_type(8))) short shortx8;
typedef __attribute__((ext_vector_type(4))) short shortx4;
typedef __attribute__((ext_vector_type(4))) float floatx4;

__device__ __forceinline__ ushort f2bf(float f) {
  unsigned u = __float_as_uint(f);
  unsigned r = (u + 0x7fffu + ((u >> 16) & 1u)) >> 16;
  return (ushort)r;
}
__device__ __forceinline__ float bf2f(ushort b) {
  return __uint_as_float(((unsigned)b) << 16);
}

__device__ __forceinline__ shortx8 pack8(float4 a, float4 b) {
  shortx8 r;
  r[0] = (short)f2bf(a.x); r[1] = (short)f2bf(a.y);
  r[2] = (short)f2bf(a.z); r[3] = (short)f2bf(a.w);
  r[4] = (short)f2bf(b.x); r[5] = (short)f2bf(b.y);
  r[6] = (short)f2bf(b.z); r[7] = (short)f2bf(b.w);
  return r;
}

__device__ __forceinline__ void async_load16(const void* g, void* l) {
  __builtin_amdgcn_global_load_lds(
      (const __attribute__((address_space(1))) void*)g,
      (__attribute__((address_space(3))) void*)l, 16, 0, 0);
}

// ---------------- reductions ----------------
__device__ __forceinline__ float block_reduce_sum_256(float v, float* sb) {
  for (int off = 32; off > 0; off >>= 1) v += __shfl_down(v, off, 64);
  int lane = threadIdx.x & 63, wid = threadIdx.x >> 6;
  if (lane == 0) sb[wid] = v;
  __syncthreads();
  return sb[0] + sb[1] + sb[2] + sb[3];
}

// ---------------- fp32 -> bf16 x4 (with zero tail padding) ----------------
__global__ __launch_bounds__(256) void cvt_bf16_k(const float* __restrict__ src,
                                                  ushort* __restrict__ dst,
                                                  size_t n_src, size_t n_dst) {
  size_t i4 = ((size_t)blockIdx.x * 256 + threadIdx.x) * 4;
  if (i4 >= n_dst) return;
  if (i4 + 4 <= n_src) {
    float4 v = *(const float4*)(src + i4);
    uint2 o;
    o.x = (uint)f2bf(v.x) | ((uint)f2bf(v.y) << 16);
    o.y = (uint)f2bf(v.z) | ((uint)f2bf(v.w) << 16);
    *(uint2*)(dst + i4) = o;
  } else {
    for (int j = 0; j < 4; j++) {
      size_t i = i4 + j;
      if (i < n_dst) dst[i] = f2bf(i < n_src ? src[i] : 0.f);
    }
  }
}

// ---------------- rmsnorm (width 1024) -> bf16 out ----------------
__global__ __launch_bounds__(256) void rmsnorm_k(const float* __restrict__ x,
                                                 const float* __restrict__ w,
                                                 ushort* __restrict__ out) {
  __shared__ float sb[4];
  int r = blockIdx.x;
  const float* xr = x + (size_t)r * DMODEL;
  ushort* orow = out + (size_t)r * DMODEL;
  int c4 = threadIdx.x * 4;
  float4 v = *(const float4*)(xr + c4);
  float ssq = v.x * v.x + v.y * v.y + v.z * v.z + v.w * v.w;
  float s = block_reduce_sum_256(ssq, sb);
  float sc = rsqrtf(s / (float)DMODEL + EPSF);
  float4 wv = *(const float4*)(w + c4);
  uint2 o;
  o.x = (uint)f2bf(v.x * sc * wv.x) | ((uint)f2bf(v.y * sc * wv.y) << 16);
  o.y = (uint)f2bf(v.z * sc * wv.z) | ((uint)f2bf(v.w * sc * wv.w) << 16);
  *(uint2*)(orow + c4) = o;
}

// ---------------- MFMA bf16 NT GEMM (128x128 tile, BK=64, XOR-swizzled LDS) ----------------
__global__ __launch_bounds__(256) void gemm_nt_mfma(const ushort* __restrict__ A,
                                                    const ushort* __restrict__ B,
                                                    float* __restrict__ C,
                                                    ushort* __restrict__ Cbf,
                                                    const float* __restrict__ resid,
                                                    int M, int N, int K) {
  __shared__ ushort Asm[128 * 64];
  __shared__ ushort Bsm[128 * 64];
  int tid = threadIdx.x;
  int wid = tid >> 6, lane = tid & 63;
  int quad = lane >> 4, lrow = lane & 15;
  int m0 = blockIdx.y * 128, n0 = blockIdx.x * 128;
  int wm = (wid >> 1) * 64, wn = (wid & 1) * 64;
  floatx4 acc[4][4];
  for (int i = 0; i < 4; i++)
    for (int j = 0; j < 4; j++) acc[i][j] = (floatx4){0.f, 0.f, 0.f, 0.f};

  for (int k0 = 0; k0 < K; k0 += 64) {
    __syncthreads();
    for (int is = 0; is < 4; is++) {
      int boff = is * 4096 + wid * 1024;
      int bb = boff + lane * 16;
      int row = bb >> 7;
      int cb = bb & 127;
      int col = (cb ^ ((row & 7) << 4)) >> 1;
      async_load16(A + (size_t)(m0 + row) * K + k0 + col, (char*)Asm + boff);
      async_load16(B + (size_t)(n0 + row) * K + k0 + col, (char*)Bsm + boff);
    }
    __syncthreads();
    for (int kk = 0; kk < 64; kk += 32) {
      shortx8 af[4], bf[4];
      for (int i = 0; i < 4; i++) {
        int r = wm + i * 16 + lrow;
        int cbyte = ((kk + quad * 8) * 2) ^ ((r & 7) << 4);
        af[i] = *(const shortx8*)((const char*)Asm + r * 128 + cbyte);
      }
      for (int j = 0; j < 4; j++) {
        int r = wn + j * 16 + lrow;
        int cbyte = ((kk + quad * 8) * 2) ^ ((r & 7) << 4);
        bf[j] = *(const shortx8*)((const char*)Bsm + r * 128 + cbyte);
      }
      for (int i = 0; i < 4; i++)
        for (int j = 0; j < 4; j++)
          acc[i][j] = __builtin_amdgcn_mfma_f32_16x16x32_bf16(af[i], bf[j], acc[i][j], 0, 0, 0);
    }
  }
  if (Cbf) {
    for (int i = 0; i < 4; i++) {
      int r0 = m0 + wm + i * 16 + quad * 4;
      for (int j = 0; j < 4; j++) {
        int n = n0 + wn + j * 16 + lrow;
        if (n < N)
          for (int r = 0; r < 4; r++)
            Cbf[(size_t)(r0 + r) * N + n] = f2bf(acc[i][j][r]);
      }
    }
  } else {
    bool hasR = (resid != nullptr);
    for (int i = 0; i < 4; i++) {
      int r0 = m0 + wm + i * 16 + quad * 4;
      for (int j = 0; j < 4; j++) {
        int n = n0 + wn + j * 16 + lrow;
        if (n < N) {
          for (int r = 0; r < 4; r++) {
            size_t idx = (size_t)(r0 + r) * N + n;
            float v = acc[i][j][r];
            if (hasR) v += resid[idx];
            C[idx] = v;
          }
        }
      }
    }
  }
}

// ---------------- depthwise conv + silu -> bf16 xBC (2 ch / thread) ----------------
__global__ __launch_bounds__(256) void conv_silu_k(const ushort* __restrict__ zxbf,
                                                   const float* __restrict__ cw,
                                                   const float* __restrict__ cb,
                                                   ushort* __restrict__ xbf) {
  int ch2 = blockIdx.x * 256 + threadIdx.x;
  if (ch2 >= CONVDIM / 2) return;
  int ch = ch2 * 2;
  int r = blockIdx.y;
  int b = r >> 11, l = r & (LSEQ - 1);
  float a0 = cb[ch], a1 = cb[ch + 1];
  for (int k = 0; k < DCONV; k++) {
    int ls = l - (DCONV - 1) + k;
    if (ls >= 0) {
      uint v = *(const uint*)(zxbf + (size_t)(b * LSEQ + ls) * DINPROJ + DINNER + ch);
      a0 += bf2f((ushort)(v & 0xffff)) * cw[ch * DCONV + k];
      a1 += bf2f((ushort)(v >> 16)) * cw[(ch + 1) * DCONV + k];
    }
  }
  a0 = a0 / (1.f + expf(-a0));
  a1 = a1 / (1.f + expf(-a1));
  *(uint*)(xbf + (size_t)r * CONVDIM + ch) = (uint)f2bf(a0) | ((uint)f2bf(a1) << 16);
}

// ---------------- fused dt softplus + per-chunk inclusive cumsum of dt*A ----------------
__global__ __launch_bounds__(256) void cumsum_k(const ushort* __restrict__ zxbf,
                                                const float* __restrict__ dt_bias,
                                                const float* __restrict__ A_log,
                                                float* __restrict__ dt_sp,
                                                float* __restrict__ dtA_cs) {
  __shared__ float buf[256];
  int bid = blockIdx.x;  // ((b*8+c)*32+h)
  int h = bid & 31, c = (bid >> 5) & 7, b = bid >> 8;
  int l = threadIdx.x;
  float Aneg = -expf(A_log[h]);
  int row = b * LSEQ + c * CHUNKSZ + l;
  float v = bf2f(zxbf[(size_t)row * DINPROJ + DINNER + CONVDIM + h]) + dt_bias[h];
  float dtv = (v > 20.f) ? v : log1pf(expf(v));
  dt_sp[row * 32 + h] = dtv;
  buf[l] = dtv * Aneg;
  __syncthreads();
  for (int off = 1; off < 256; off <<= 1) {
    float add = (l >= off) ? buf[l - off] : 0.f;
    __syncthreads();
    buf[l] += add;
    __syncthreads();
  }
  dtA_cs[(size_t)bid * CHUNKSZ + l] = buf[l];
}

// ---------------- MFMA per-chunk end states: st[p][n] = sum_l (Xdt*decay)[l,p] B[l,n] ----------------
#define ST_STRIDE 72
__global__ __launch_bounds__(256) void states_mfma(const ushort* __restrict__ xbf,
                                                   const float* __restrict__ dt_sp,
                                                   const float* __restrict__ dtA_cs,
                                                   float* __restrict__ st_raw) {
  __shared__ ushort XT[64 * ST_STRIDE];  // [p][l] bf16
  __shared__ ushort BT[64 * ST_STRIDE];  // [n][l] bf16
  __shared__ float wrow[64];
  int bid = blockIdx.x;  // ((b*8+c)*32+h)
  int h = bid & 31, c = (bid >> 5) & 7, b = bid >> 8;
  int tid = threadIdx.x;
  int w = tid >> 6, lane = tid & 63;
  int quad = lane >> 4, lrow = lane & 15;
  int cbase = bid * CHUNKSZ;
  int rowbase = b * LSEQ + c * CHUNKSZ;
  float T = dtA_cs[cbase + CHUNKSZ - 1];
  floatx4 acc[4];
  for (int jt = 0; jt < 4; jt++) acc[jt] = (floatx4){0.f, 0.f, 0.f, 0.f};
  int half = tid & 31, srb = tid >> 5;
  for (int lt = 0; lt < 4; lt++) {
    __syncthreads();
    if (tid < 64) {
      int row = rowbase + lt * 64 + tid;
      wrow[tid] = dt_sp[row * 32 + h] * __expf(T - dtA_cs[cbase + lt * 64 + tid]);
    }
    __syncthreads();
    for (int pass = 0; pass < 8; pass++) {
      int sr = srb + pass * 8;
      int row = rowbase + lt * 64 + sr;
      uint bv = *(const uint*)(xbf + (size_t)row * CONVDIM + DINNER + 2 * half);
      uint xv = *(const uint*)(xbf + (size_t)row * CONVDIM + h * DHEAD + 2 * half);
      float wv = wrow[sr];
      BT[(2 * half) * ST_STRIDE + sr]     = (ushort)(bv & 0xffff);
      BT[(2 * half + 1) * ST_STRIDE + sr] = (ushort)(bv >> 16);
      XT[(2 * half) * ST_STRIDE + sr]     = f2bf(bf2f((ushort)(xv & 0xffff)) * wv);
      XT[(2 * half + 1) * ST_STRIDE + sr] = f2bf(bf2f((ushort)(xv >> 16)) * wv);
    }
    __syncthreads();
    for (int kk = 0; kk < 64; kk += 32) {
      shortx8 af = *(const shortx8*)&XT[(w * 16 + lrow) * ST_STRIDE + kk + quad * 8];
      for (int jt = 0; jt < 4; jt++) {
        shortx8 bf = *(const shortx8*)&BT[(jt * 16 + lrow) * ST_STRIDE + kk + quad * 8];
        acc[jt] = __builtin_amdgcn_mfma_f32_16x16x32_bf16(af, bf, acc[jt], 0, 0, 0);
      }
    }
  }
  size_t base = (size_t)bid * (DHEAD * DSTATE);
  for (int jt = 0; jt < 4; jt++) {
    int n = jt * 16 + lrow;
    for (int r = 0; r < 4; r++) {
      int p = w * 16 + quad * 4 + r;
      st_raw[base + (size_t)p * 64 + n] = acc[jt][r];
    }
  }
}

// ---------------- inter-chunk scan (in-place) ----------------
__global__ __launch_bounds__(256) void scan_k(float* __restrict__ st,
                                              const float* __restrict__ dtA_cs) {
  int bid = blockIdx.x;
  int h = bid & 31, b = bid >> 5;
  int tid = threadIdx.x;
  float s[16];
  for (int i = 0; i < 16; i++) s[i] = 0.f;
  for (int c = 0; c < NCHUNK; c++) {
    int g = (b * NCHUNK + c) * 32 + h;
    float dec = expf(dtA_cs[(size_t)g * CHUNKSZ + CHUNKSZ - 1]);
    size_t base = (size_t)g * (DHEAD * DSTATE);
    for (int i = 0; i < 16; i++) {
      int idx = tid + i * 256;
      float raw = st[base + idx];
      st[base + idx] = s[i];
      s[i] = s[i] * dec + raw;
    }
  }
}

// ---------------- MFMA ydiag, one block per (b,c,h): wave w = 64-row band lt=w ----------------
// Each s-tile staged ONCE; waves with w>=st consume it. Y = P@Xdt + e^cs (C st^T).
#define BS_STRIDE 72
#define XT_STRIDE 68
#define PW_STRIDE 72
__global__ __launch_bounds__(256) void ydiag_mfma(const ushort* __restrict__ xbf,
                                                  const float* __restrict__ dt_sp,
                                                  const float* __restrict__ dtA_cs,
                                                  const float* __restrict__ st_in,
                                                  ushort* __restrict__ Y) {
  __shared__ ushort Bs[64 * BS_STRIDE];
  __shared__ ushort XsT[64 * XT_STRIDE];
  __shared__ ushort Pw[4 * 16 * PW_STRIDE];
  __shared__ float cs[256];
  int tid = threadIdx.x;
  int w = tid >> 6, lane = tid & 63;
  int quad = lane >> 4, lrow = lane & 15;
  int bid = blockIdx.x;  // ((b*8+c)*32+h)
  int h = bid & 31, c = (bid >> 5) & 7, b = bid >> 8;
  int g = bid;
  int cbase = g * CHUNKSZ;
  int rowbase = b * LSEQ + c * CHUNKSZ;

  cs[tid] = dtA_cs[cbase + tid];
  __syncthreads();

  int band = w * 64;  // wave's chunk-local base row
  shortx8 Cf[4][2];
  float csl[4][4];
  for (int mi = 0; mi < 4; mi++) {
    const ushort* cp = xbf + (size_t)(rowbase + band + mi * 16 + lrow) * CONVDIM + DINNER + DSTATE;
    Cf[mi][0] = *(const shortx8*)(cp + quad * 8);
    Cf[mi][1] = *(const shortx8*)(cp + 32 + quad * 8);
    for (int r = 0; r < 4; r++) csl[mi][r] = cs[band + mi * 16 + quad * 4 + r];
  }

  // Y_off: acc = C @ st_in^T, scaled by exp(cs_l)
  floatx4 acc[4][4];
  for (int mi = 0; mi < 4; mi++)
    for (int jt = 0; jt < 4; jt++) acc[mi][jt] = (floatx4){0.f, 0.f, 0.f, 0.f};
  const float* stp = st_in + (size_t)g * (DHEAD * DSTATE);
  for (int q = 0; q < 2; q++) {
    for (int jt = 0; jt < 4; jt++) {
      const float* sp = stp + (size_t)(jt * 16 + lrow) * 64 + q * 32 + quad * 8;
      shortx8 sf = pack8(*(const float4*)sp, *(const float4*)(sp + 4));
      for (int mi = 0; mi < 4; mi++)
        acc[mi][jt] = __builtin_amdgcn_mfma_f32_16x16x32_bf16(Cf[mi][q], sf, acc[mi][jt], 0, 0, 0);
    }
  }
  for (int mi = 0; mi < 4; mi++)
    for (int jt = 0; jt < 4; jt++)
      for (int r = 0; r < 4; r++) acc[mi][jt][r] *= __expf(csl[mi][r]);

  ushort* myP = Pw + w * 16 * PW_STRIDE;
  int half = tid & 31, srb = tid >> 5;
  for (int st = 0; st < 4; st++) {
    __syncthreads();
    for (int pass = 0; pass < 8; pass++) {
      int sr = srb + pass * 8;
      int row = rowbase + st * 64 + sr;
      uint bv = *(const uint*)(xbf + (size_t)row * CONVDIM + DINNER + 2 * half);
      *(uint*)&Bs[sr * BS_STRIDE + 2 * half] = bv;
      float dtv = dt_sp[row * 32 + h];
      uint xv = *(const uint*)(xbf + (size_t)row * CONVDIM + h * DHEAD + 2 * half);
      XsT[(2 * half) * XT_STRIDE + sr]     = f2bf(bf2f((ushort)(xv & 0xffff)) * dtv);
      XsT[(2 * half + 1) * XT_STRIDE + sr] = f2bf(bf2f((ushort)(xv >> 16)) * dtv);
    }
    __syncthreads();
    if (w < st) continue;  // wave-uniform; all waves still reach next barrier
    for (int mi = 0; mi < 4; mi++) {
      for (int jt = 0; jt < 4; jt++) {
        floatx4 s = (floatx4){0.f, 0.f, 0.f, 0.f};
        for (int q = 0; q < 2; q++) {
          shortx8 bfr = *(const shortx8*)&Bs[(jt * 16 + lrow) * BS_STRIDE + q * 32 + quad * 8];
          s = __builtin_amdgcn_mfma_f32_16x16x32_bf16(Cf[mi][q], bfr, s, 0, 0, 0);
        }
        int scol = st * 64 + jt * 16 + lrow;
        float css = cs[scol];
        for (int r = 0; r < 4; r++) {
          int l = band + mi * 16 + quad * 4 + r;
          float v = (scol <= l) ? s[r] * __expf(csl[mi][r] - css) : 0.f;
          myP[(quad * 4 + r) * PW_STRIDE + jt * 16 + lrow] = f2bf(v);
        }
      }
      shortx8 pf[2];
      for (int q = 0; q < 2; q++)
        pf[q] = *(const shortx8*)&myP[lrow * PW_STRIDE + q * 32 + quad * 8];
      for (int jt = 0; jt < 4; jt++) {
        for (int q = 0; q < 2; q++) {
          const ushort* xp = &XsT[(jt * 16 + lrow) * XT_STRIDE + q * 32 + quad * 8];
          shortx4 lo = *(const shortx4*)xp;
          shortx4 hi = *(const shortx4*)(xp + 4);
          shortx8 xf = __builtin_shufflevector(lo, hi, 0, 1, 2, 3, 4, 5, 6, 7);
          acc[mi][jt] = __builtin_amdgcn_mfma_f32_16x16x32_bf16(pf[q], xf, acc[mi][jt], 0, 0, 0);
        }
      }
    }
  }
  for (int mi = 0; mi < 4; mi++) {
    int growb = rowbase + band + mi * 16 + quad * 4;
    for (int jt = 0; jt < 4; jt++)
      for (int r = 0; r < 4; r++)
        Y[(size_t)(growb + r) * DINNER + h * DHEAD + jt * 16 + lrow] = f2bf(acc[mi][jt][r]);
  }
}

// ---------------- gated rmsnorm (+ D*X skip) -> bf16 out (2 ch / iter) ----------------
__global__ __launch_bounds__(256) void gatenorm_k(const ushort* __restrict__ Ybf,
                                                  const ushort* __restrict__ zxbf,
                                                  const ushort* __restrict__ xbf,
                                                  const float* __restrict__ Dvec,
                                                  const float* __restrict__ gw,
                                                  ushort* __restrict__ obf) {
  __shared__ float sb[4];
  int r = blockIdx.x;
  const ushort* yr = Ybf + (size_t)r * DINNER;
  const ushort* zr = zxbf + (size_t)r * DINPROJ;
  const ushort* xr = xbf + (size_t)r * CONVDIM;
  ushort* orow = obf + (size_t)r * DINNER;
  float t[8]; float ssq = 0.f;
  for (int i = 0; i < 4; i++) {
    int ch = (threadIdx.x + i * 256) * 2;
    uint zv = *(const uint*)(zr + ch);
    uint yv = *(const uint*)(yr + ch);
    uint xv = *(const uint*)(xr + ch);
    float Dh = Dvec[ch >> 6];
    float z0 = bf2f((ushort)(zv & 0xffff)), z1 = bf2f((ushort)(zv >> 16));
    float y0 = bf2f((ushort)(yv & 0xffff)) + Dh * bf2f((ushort)(xv & 0xffff));
    float y1 = bf2f((ushort)(yv >> 16)) + Dh * bf2f((ushort)(xv >> 16));
    float g0 = y0 * (z0 / (1.f + expf(-z0)));
    float g1 = y1 * (z1 / (1.f + expf(-z1)));
    t[2 * i] = g0; t[2 * i + 1] = g1;
    ssq += g0 * g0 + g1 * g1;
  }
  float s = block_reduce_sum_256(ssq, sb);
  float sc = rsqrtf(s / (float)DINNER + EPSF);
  for (int i = 0; i < 4; i++) {
    int ch = (threadIdx.x + i * 256) * 2;
    uint o = (uint)f2bf(t[2 * i] * sc * gw[ch]) |
             ((uint)f2bf(t[2 * i + 1] * sc * gw[ch + 1]) << 16);
    *(uint*)(orow + ch) = o;
  }
}

// ---------------- launch ----------------
extern "C" void kernel_launch(void* const* d_in, const int* in_sizes, int n_in,
                              void* d_out, int out_size, void* d_ws, size_t ws_size,
                              hipStream_t stream) {
  const float* x_in     = (const float*)d_in[0];
  const float* in_w     = (const float*)d_in[1];
  const float* conv_w   = (const float*)d_in[2];
  const float* conv_b   = (const float*)d_in[3];
  const float* dt_bias  = (const float*)d_in[4];
  const float* A_log    = (const float*)d_in[5];
  const float* Dvec     = (const float*)d_in[6];
  const float* gnorm_w  = (const float*)d_in[7];
  const float* out_w    = (const float*)d_in[8];
  const float* rms_w    = (const float*)d_in[9];
  float* out = (float*)d_out;

  float* ws = (float*)d_ws;
  size_t o = 0;
  float* x_cur  = ws + o; o += (size_t)MROWS * DMODEL;
  ushort* zx_bf = (ushort*)(ws + o); o += (size_t)MROWS * DINPROJ / 2;
  ushort* xbf   = (ushort*)(ws + o); o += (size_t)MROWS * CONVDIM / 2;
  float* dt_sp  = ws + o; o += (size_t)MROWS * NHEADS;
  float* dtA_cs = ws + o; o += (size_t)BATCH * NCHUNK * NHEADS * CHUNKSZ;
  float* st     = ws + o; o += (size_t)BATCH * NCHUNK * NHEADS * DHEAD * DSTATE;
  ushort* Ybf   = (ushort*)(ws + o); o += (size_t)MROWS * DINNER / 2;
  ushort* act_bf = (ushort*)(ws + o); o += (size_t)MROWS * DINNER / 2;
  ushort* w_bf   = (ushort*)(ws + o); o += (size_t)DINPROJ_PAD * DMODEL / 2;

  hipMemcpyAsync(x_cur, x_in, (size_t)MROWS * DMODEL * sizeof(float),
                 hipMemcpyDeviceToDevice, stream);

  for (int i = 0; i < 4; i++) {
    const float* in_w_i   = in_w    + (size_t)i * DINPROJ * DMODEL;
    const float* conv_w_i = conv_w  + (size_t)i * CONVDIM * DCONV;
    const float* conv_b_i = conv_b  + (size_t)i * CONVDIM;
    const float* dtb_i    = dt_bias + (size_t)i * NHEADS;
    const float* Alog_i   = A_log   + (size_t)i * NHEADS;
    const float* D_i      = Dvec    + (size_t)i * NHEADS;
    const float* gw_i     = gnorm_w + (size_t)i * DINNER;
    const float* out_w_i  = out_w   + (size_t)i * DMODEL * DINNER;
    const float* rms_w_i  = rms_w   + (size_t)i * DMODEL;

    {
      size_t ns = (size_t)DINPROJ * DMODEL, nd = (size_t)DINPROJ_PAD * DMODEL;
      cvt_bf16_k<<<(nd / 4 + 255) / 256, 256, 0, stream>>>(in_w_i, w_bf, ns, nd);
    }
    rmsnorm_k<<<MROWS, 256, 0, stream>>>(x_cur, rms_w_i, act_bf);
    gemm_nt_mfma<<<dim3(DINPROJ_PAD / 128, MROWS / 128), 256, 0, stream>>>(
        act_bf, w_bf, nullptr, zx_bf, nullptr, MROWS, DINPROJ, DMODEL);
    conv_silu_k<<<dim3((CONVDIM / 2 + 255) / 256, MROWS), 256, 0, stream>>>(
        zx_bf, conv_w_i, conv_b_i, xbf);
    cumsum_k<<<BATCH * NCHUNK * NHEADS, 256, 0, stream>>>(zx_bf, dtb_i, Alog_i, dt_sp, dtA_cs);
    states_mfma<<<BATCH * NCHUNK * NHEADS, 256, 0, stream>>>(xbf, dt_sp, dtA_cs, st);
    scan_k<<<BATCH * NHEADS, 256, 0, stream>>>(st, dtA_cs);
    ydiag_mfma<<<BATCH * NCHUNK * NHEADS, 256, 0, stream>>>(
        xbf, dt_sp, dtA_cs, st, Ybf);
    gatenorm_k<<<MROWS, 256, 0, stream>>>(Ybf, zx_bf, xbf, D_i, gw_i, act_bf);
    {
      size_t ns = (size_t)DMODEL * DINNER;
      cvt_bf16_k<<<(ns / 4 + 255) / 256, 256, 0, stream>>>(out_w_i, w_bf, ns, ns);
    }
    float* outC = (i == 3) ? out : x_cur;
    gemm_nt_mfma<<<dim3(DMODEL / 128, MROWS / 128), 256, 0, stream>>>(
        act_bf, w_bf, outC, nullptr, x_cur, MROWS, DMODEL, DINNER);
  }
}